// Round 1
// baseline (1480.149 us; speedup 1.0000x reference)
//
#include <hip/hip_runtime.h>
#include <math.h>

#define N_FILT   80
#define FILT_DIM 251
#define KPAD     256          // filter taps padded to 256 with zeros
#define SIG_LEN  32000
#define OUT_LEN  (SIG_LEN - FILT_DIM + 1)   // 31750
#define BATCH    32
#define TILE_OUT 2048
#define TPB      256

#define TWO_PI_F 6.28318530717958647692f

// ---------------------------------------------------------------------------
// Kernel 1: build the 80 sinc band-pass filters (251 taps, padded to 256).
// tap(i) for filter f:  m = |i-125|
//   bp = 2*fe*sinc(2*pi*fe*m) - 2*fb*sinc(2*pi*fb*m)   (sinc(0)=1)
//   out = bp / max_i(bp) * (0.54 - 0.46*cos(2*pi*i/250))
// ---------------------------------------------------------------------------
__global__ __launch_bounds__(TPB) void build_filters_kernel(
    const float* __restrict__ b1, const float* __restrict__ band,
    float* __restrict__ filt)
{
    const int f = blockIdx.x;
    const int i = threadIdx.x;

    const float MINF = 50.0f / 16000.0f;
    const float fb = fabsf(b1[f]) + MINF;
    const float fe = fb + fabsf(band[f]) + MINF;

    float v = 0.0f;
    if (i < FILT_DIM) {
        int m = i - 125;
        m = (m < 0) ? -m : m;
        if (m == 0) {
            v = 2.0f * fe - 2.0f * fb;
        } else {
            float a1 = TWO_PI_F * fb * (float)m;
            float a2 = TWO_PI_F * fe * (float)m;
            v = 2.0f * fe * (sinf(a2) / a2) - 2.0f * fb * (sinf(a1) / a1);
        }
    }

    __shared__ float red[TPB];
    red[i] = (i < FILT_DIM) ? v : -INFINITY;
    __syncthreads();
    #pragma unroll
    for (int s = TPB / 2; s > 0; s >>= 1) {
        if (i < s) red[i] = fmaxf(red[i], red[i + s]);
        __syncthreads();
    }
    const float mx = red[0];

    const float w = 0.54f - 0.46f * cosf(TWO_PI_F * (float)i / 250.0f);
    filt[f * KPAD + i] = (i < FILT_DIM) ? (v / mx) * w : 0.0f;
}

// ---------------------------------------------------------------------------
// Kernel 2: valid 1-D cross-correlation.
//   out[n,f,t] = sum_k filt[f,k] * x[n,t+k],  t in [0, 31750)
// Block = one (n, f) pair x TILE_OUT outputs. x tile + filter staged in LDS.
// Each thread: 8 consecutive outputs, 16-wide circular register window
// (no per-iteration register shifts), ds_read_b128 for x and filter.
// ---------------------------------------------------------------------------
__global__ __launch_bounds__(TPB) void sinc_conv_kernel(
    const float* __restrict__ x, const float* __restrict__ filt,
    float* __restrict__ out)
{
    __shared__ float xs[TILE_OUT + KPAD + 16];   // 2320 floats
    __shared__ float fs[KPAD];

    const int tile = blockIdx.x;
    const int f    = blockIdx.y;
    const int n    = blockIdx.z;
    const int t0   = tile * TILE_OUT;
    const float* xp = x + (size_t)n * SIG_LEN;

    // stage filter (256 floats = 64 float4)
    if (threadIdx.x < KPAD / 4)
        ((float4*)fs)[threadIdx.x] = ((const float4*)(filt + (size_t)f * KPAD))[threadIdx.x];

    // stage x tile, zero-fill past end of signal
    for (int i = threadIdx.x; i < TILE_OUT + KPAD + 16; i += TPB) {
        int gi = t0 + i;
        xs[i] = (gi < SIG_LEN) ? xp[gi] : 0.0f;
    }
    __syncthreads();

    const int tl = threadIdx.x * 8;   // 8 consecutive outputs per thread
    float acc[8] = {0.f, 0.f, 0.f, 0.f, 0.f, 0.f, 0.f, 0.f};
    float w[16];
    {
        float4 a = *(const float4*)(xs + tl);
        float4 b = *(const float4*)(xs + tl + 4);
        w[0] = a.x; w[1] = a.y; w[2] = a.z; w[3] = a.w;
        w[4] = b.x; w[5] = b.y; w[6] = b.z; w[7] = b.w;
    }

    for (int k = 0; k < KPAD; k += 16) {
        // first half: new x -> w[8..15], window starts at w[0]
        {
            float4 c  = *(const float4*)(xs + tl + k + 8);
            float4 d  = *(const float4*)(xs + tl + k + 12);
            float4 f0 = *(const float4*)(fs + k);
            float4 f1 = *(const float4*)(fs + k + 4);
            w[8]  = c.x; w[9]  = c.y; w[10] = c.z; w[11] = c.w;
            w[12] = d.x; w[13] = d.y; w[14] = d.z; w[15] = d.w;
            float ff[8] = {f0.x, f0.y, f0.z, f0.w, f1.x, f1.y, f1.z, f1.w};
            #pragma unroll
            for (int kk = 0; kk < 8; ++kk)
                #pragma unroll
                for (int r = 0; r < 8; ++r)
                    acc[r] = fmaf(ff[kk], w[kk + r], acc[r]);
        }
        // second half: new x -> w[0..7], window starts at w[8] (circular)
        {
            float4 c  = *(const float4*)(xs + tl + k + 16);
            float4 d  = *(const float4*)(xs + tl + k + 20);
            float4 f0 = *(const float4*)(fs + k + 8);
            float4 f1 = *(const float4*)(fs + k + 12);
            w[0] = c.x; w[1] = c.y; w[2] = c.z; w[3] = c.w;
            w[4] = d.x; w[5] = d.y; w[6] = d.z; w[7] = d.w;
            float ff[8] = {f0.x, f0.y, f0.z, f0.w, f1.x, f1.y, f1.z, f1.w};
            #pragma unroll
            for (int kk = 0; kk < 8; ++kk)
                #pragma unroll
                for (int r = 0; r < 8; ++r)
                    acc[r] = fmaf(ff[kk], w[(8 + kk + r) & 15], acc[r]);
        }
    }

    // store: row stride 31750 is 8B-aligned -> float2 stores, pair-granular guard
    const size_t base = ((size_t)n * N_FILT + f) * OUT_LEN;
    const int tg = t0 + tl;
    #pragma unroll
    for (int r = 0; r < 8; r += 2) {
        int t = tg + r;
        if (t < OUT_LEN)
            *(float2*)(out + base + t) = make_float2(acc[r], acc[r + 1]);
    }
}

// ---------------------------------------------------------------------------
extern "C" void kernel_launch(void* const* d_in, const int* in_sizes, int n_in,
                              void* d_out, int out_size, void* d_ws, size_t ws_size,
                              hipStream_t stream)
{
    const float* x    = (const float*)d_in[0];
    const float* b1   = (const float*)d_in[1];
    const float* band = (const float*)d_in[2];
    float* outp = (float*)d_out;
    float* filt = (float*)d_ws;    // 80 * 256 * 4 B = 80 KB scratch

    build_filters_kernel<<<dim3(N_FILT), dim3(TPB), 0, stream>>>(b1, band, filt);

    dim3 grid((OUT_LEN + TILE_OUT - 1) / TILE_OUT, N_FILT, BATCH);  // 16 x 80 x 32
    sinc_conv_kernel<<<grid, dim3(TPB), 0, stream>>>(x, filt, outp);
}

// Round 2
// 453.356 us; speedup vs baseline: 3.2649x; 3.2649x over previous
//
#include <hip/hip_runtime.h>
#include <math.h>

#define N_FILT   80
#define FILT_DIM 251
#define KPAD     256
#define SIG_LEN  32000
#define OUT_LEN  31750
#define BATCH    32
#define TPB      256

#define STRIP    1024      // t-range per block
#define WAVE_T   256       // t-range per wave (4 waves)
#define NT       16        // 16x16 tiles per wave
#define LROW     658       // dwords per replica row: %4==2 (8B align), %32==18 (bank spread)

#define TWO_PI_F 6.28318530717958647692f

typedef __attribute__((ext_vector_type(8))) short  short8;   // 8 bf16 (A/B frag)
typedef __attribute__((ext_vector_type(4))) float  float4v;  // C/D frag

__device__ inline unsigned short f2bf(float v) {             // fp32 -> bf16 RNE
    unsigned u = __float_as_uint(v);
    return (unsigned short)((u + 0x7fffu + ((u >> 16) & 1u)) >> 16);
}
__device__ inline float bf2f(unsigned short h) {
    return __uint_as_float(((unsigned)h) << 16);
}

// ---------------------------------------------------------------------------
// Kernel 1: build 80 sinc band-pass filters, split each tap into bf16 hi+lo.
// Layout: fh[80][256], fl[80][256] (k padded with zeros) in d_ws.
// ---------------------------------------------------------------------------
__global__ __launch_bounds__(TPB) void build_filters_kernel(
    const float* __restrict__ b1, const float* __restrict__ band,
    unsigned short* __restrict__ fh, unsigned short* __restrict__ fl)
{
    const int f = blockIdx.x;
    const int i = threadIdx.x;

    const float MINF = 50.0f / 16000.0f;
    const float fb = fabsf(b1[f]) + MINF;
    const float fe = fb + fabsf(band[f]) + MINF;

    float v = 0.0f;
    if (i < FILT_DIM) {
        int m = i - 125; m = (m < 0) ? -m : m;
        if (m == 0) v = 2.0f * fe - 2.0f * fb;
        else {
            float a1 = TWO_PI_F * fb * (float)m;
            float a2 = TWO_PI_F * fe * (float)m;
            v = 2.0f * fe * (sinf(a2) / a2) - 2.0f * fb * (sinf(a1) / a1);
        }
    }

    __shared__ float red[TPB];
    red[i] = (i < FILT_DIM) ? v : -INFINITY;
    __syncthreads();
    #pragma unroll
    for (int s = TPB / 2; s > 0; s >>= 1) {
        if (i < s) red[i] = fmaxf(red[i], red[i + s]);
        __syncthreads();
    }
    const float mx = red[0];

    const float w   = 0.54f - 0.46f * cosf(TWO_PI_F * (float)i / 250.0f);
    const float val = (i < FILT_DIM) ? (v / mx) * w : 0.0f;
    const unsigned short h = f2bf(val);
    const unsigned short l = f2bf(val - bf2f(h));
    fh[f * KPAD + i] = h;
    fl[f * KPAD + i] = (i < FILT_DIM) ? l : 0;
}

// ---------------------------------------------------------------------------
// Kernel 2: conv as MFMA GEMM.  C[f,t] = sum_k F[f,k] * x[t+k]
//   A (16 f x 32 k)  = filters, register-resident bf16 hi/lo fragments
//   B (32 k x 16 t)  = Toeplitz x from LDS; 4 shift-replicated bf16 copies
//                      so every lane's 8-element window is 8B-aligned.
//   3-MFMA split: fh*xh + fh*xl + fl*xh  (lo*lo dropped)
// Block: 4 waves x 256 t = 1024 t, one f-block (16 filters), one batch n.
// ---------------------------------------------------------------------------
__global__ __launch_bounds__(TPB) void sinc_mfma_kernel(
    const float* __restrict__ x,
    const unsigned short* __restrict__ fh, const unsigned short* __restrict__ fl,
    float* __restrict__ out)
{
    __shared__ unsigned xh[4 * LROW];   // 4 replicas, bf16-pairs packed in dwords
    __shared__ unsigned xl[4 * LROW];

    const int tid   = threadIdx.x;
    const int strip = blockIdx.x;
    const int fb    = blockIdx.y;
    const int n     = blockIdx.z;
    const int e0    = strip * STRIP;
    const float* xp = x + (size_t)n * SIG_LEN;

    // ---- stage x: bf16 hi/lo, 4 shifted replicas (copy r holds x[e0+e+r]) --
    for (int d = tid; d < 644; d += TPB) {
        const int g = e0 + 2 * d;
        float v0, v1, v2;
        if (g + 2 < SIG_LEN) {
            float2 p = *(const float2*)(xp + g);
            v0 = p.x; v1 = p.y; v2 = xp[g + 2];
        } else {
            v0 = (g     < SIG_LEN) ? xp[g]     : 0.0f;
            v1 = (g + 1 < SIG_LEN) ? xp[g + 1] : 0.0f;
            v2 = (g + 2 < SIG_LEN) ? xp[g + 2] : 0.0f;
        }
        const unsigned short h0 = f2bf(v0), h1 = f2bf(v1), h2 = f2bf(v2);
        const unsigned short l0 = f2bf(v0 - bf2f(h0));
        const unsigned short l1 = f2bf(v1 - bf2f(h1));
        const unsigned short l2 = f2bf(v2 - bf2f(h2));
        const unsigned pe_h = (unsigned)h0 | ((unsigned)h1 << 16);
        const unsigned po_h = (unsigned)h1 | ((unsigned)h2 << 16);
        const unsigned pe_l = (unsigned)l0 | ((unsigned)l1 << 16);
        const unsigned po_l = (unsigned)l1 | ((unsigned)l2 << 16);
        xh[0 * LROW + d] = pe_h;           // copy0: elems 2d,2d+1
        xh[1 * LROW + d] = po_h;           // copy1: elems 2d+1,2d+2 (shift 1)
        xl[0 * LROW + d] = pe_l;
        xl[1 * LROW + d] = po_l;
        if (d >= 1) {
            xh[2 * LROW + d - 1] = pe_h;   // copy2: shift 2
            xh[3 * LROW + d - 1] = po_h;   // copy3: shift 3
            xl[2 * LROW + d - 1] = pe_l;
            xl[3 * LROW + d - 1] = po_l;
        }
    }

    // ---- A fragments: 16 filters x 256 k, bf16 hi/lo, from global ----------
    const int lane = tid & 63;
    const int w    = tid >> 6;
    const int m    = lane & 15;       // A-row (f) / B-col (t) / C-col (t)
    const int q    = lane >> 4;       // quad: k = q*8+j ; C-row = q*4+reg
    short8 Ah[8], Al[8];
    {
        const unsigned short* ph = fh + (fb * 16 + m) * KPAD + q * 8;
        const unsigned short* pl = fl + (fb * 16 + m) * KPAD + q * 8;
        #pragma unroll
        for (int kb = 0; kb < 8; ++kb) {
            Ah[kb] = *(const short8*)(ph + kb * 32);
            Al[kb] = *(const short8*)(pl + kb * 32);
        }
    }
    __syncthreads();

    // ---- main loop ---------------------------------------------------------
    // element start s = 256w + 16tt + m + 8q + 32kb ; replica r = m&3
    // dword idx = LROW*r + (s-r)/2
    const int r = m & 3;
    const unsigned base = (unsigned)(r * LROW + 2 * (m >> 2) + 4 * q + 128 * w);

    for (int tt = 0; tt < NT; ++tt) {
        float4v ahh = {0.f, 0.f, 0.f, 0.f};
        float4v ahl = {0.f, 0.f, 0.f, 0.f};
        float4v alh = {0.f, 0.f, 0.f, 0.f};
        const unsigned bofs = base + 8 * tt;

        #pragma unroll
        for (int kb = 0; kb < 8; ++kb) {
            const unsigned o = bofs + 16 * kb;
            const uint2 a0 = *(const uint2*)(&xh[o]);
            const uint2 a1 = *(const uint2*)(&xh[o + 2]);
            const uint2 b0 = *(const uint2*)(&xl[o]);
            const uint2 b1 = *(const uint2*)(&xl[o + 2]);
            union { unsigned u[4]; short8 s; } Bh, Bl;
            Bh.u[0] = a0.x; Bh.u[1] = a0.y; Bh.u[2] = a1.x; Bh.u[3] = a1.y;
            Bl.u[0] = b0.x; Bl.u[1] = b0.y; Bl.u[2] = b1.x; Bl.u[3] = b1.y;
            ahh = __builtin_amdgcn_mfma_f32_16x16x32_bf16(Ah[kb], Bh.s, ahh, 0, 0, 0);
            ahl = __builtin_amdgcn_mfma_f32_16x16x32_bf16(Ah[kb], Bl.s, ahl, 0, 0, 0);
            alh = __builtin_amdgcn_mfma_f32_16x16x32_bf16(Al[kb], Bh.s, alh, 0, 0, 0);
        }

        const int t = e0 + w * WAVE_T + tt * 16 + m;   // C col
        if (t < OUT_LEN) {
            const size_t rowbase =
                ((size_t)n * N_FILT + fb * 16 + q * 4) * OUT_LEN + t;
            #pragma unroll
            for (int rg = 0; rg < 4; ++rg)
                out[rowbase + (size_t)rg * OUT_LEN] = ahh[rg] + ahl[rg] + alh[rg];
        }
    }
}

// ---------------------------------------------------------------------------
extern "C" void kernel_launch(void* const* d_in, const int* in_sizes, int n_in,
                              void* d_out, int out_size, void* d_ws, size_t ws_size,
                              hipStream_t stream)
{
    const float* x    = (const float*)d_in[0];
    const float* b1   = (const float*)d_in[1];
    const float* band = (const float*)d_in[2];
    float* outp = (float*)d_out;

    unsigned short* fh = (unsigned short*)d_ws;          // 80*256*2 B
    unsigned short* fl = fh + N_FILT * KPAD;             // 80*256*2 B (total 80 KB)

    build_filters_kernel<<<dim3(N_FILT), dim3(TPB), 0, stream>>>(b1, band, fh, fl);

    dim3 grid((OUT_LEN + STRIP - 1) / STRIP, N_FILT / 16, BATCH);   // 32 x 5 x 32
    sinc_mfma_kernel<<<grid, dim3(TPB), 0, stream>>>(x, fh, fl, outp);
}